// Round 13
// baseline (261.945 us; speedup 1.0000x reference)
//
#include <hip/hip_runtime.h>

#define S_LEN 2048
#define NH 32
#define NKV 8
#define HD 64
#define QH_DIM (NH * HD)    // 2048
#define QKV_DIM 3072        // 2048 Q + 512 K + 512 V
#define K_OFF 2048
#define V_OFF 2560
#define LOG2E 1.44269504089f

typedef __attribute__((ext_vector_type(8))) __bf16 bf16x8;
typedef __attribute__((ext_vector_type(4))) float fx4;
typedef __attribute__((ext_vector_type(8))) unsigned short ush8;

__device__ __forceinline__ unsigned short f2bf(float f) {
  return __builtin_bit_cast(unsigned short, (__bf16)f);  // RNE; pairs fuse to v_cvt_pk_bf16_f32
}
__device__ __forceinline__ float bf2f(unsigned short h) {
  unsigned int u = ((unsigned int)h) << 16;
  return __builtin_bit_cast(float, u);
}
__device__ __forceinline__ fx4 zero4() {
  fx4 z; z[0] = 0.f; z[1] = 0.f; z[2] = 0.f; z[3] = 0.f; return z;
}

#define MFMA16(a, b, c) __builtin_amdgcn_mfma_f32_16x16x32_bf16((a), (b), (c), 0, 0, 0)

__device__ __forceinline__ void gl16(const void* g, void* l) {
  __builtin_amdgcn_global_load_lds((const __attribute__((address_space(1))) void*)g,
                                   (__attribute__((address_space(3))) void*)l, 16, 0, 0);
}

// ---------------- fused cast fp32 -> bf16 for 5 tensors ----------------
__global__ __launch_bounds__(256) void cast5(const float* __restrict__ s0, unsigned short* d0, int n0,
                                             const float* __restrict__ s1, unsigned short* d1, int n1,
                                             const float* __restrict__ s2, unsigned short* d2, int n2,
                                             const float* __restrict__ s3, unsigned short* d3, int n3,
                                             const float* __restrict__ s4, unsigned short* d4, int n4) {
  int i = blockIdx.x * 256 + threadIdx.x;
  const float* s;
  unsigned short* d;
  if (i < n0) { s = s0; d = d0; }
  else if ((i -= n0) < n1) { s = s1; d = d1; }
  else if ((i -= n1) < n2) { s = s2; d = d2; }
  else if ((i -= n2) < n3) { s = s3; d = d3; }
  else if ((i -= n3) < n4) { s = s4; d = d4; }
  else return;
  float4 v = ((const float4*)s)[i];
  ushort4 o;
  o.x = f2bf(v.x); o.y = f2bf(v.y); o.z = f2bf(v.z); o.w = f2bf(v.w);
  ((ushort4*)d)[i] = o;
}

// ---------------- split-K GEMM: Part[z][M][N] (bf16) = A[M][Kz] * B[N][Kz]^T ----
// 128x128 tile, BK=32, 8 waves, double-buffered 2-phase pipeline, 32 KB LDS.
// KH = K / nslices (grid.z). launch_bounds(512,6): VGPR<=85, 3 blocks/CU.
__global__ __launch_bounds__(512, 6) void gemm_split(const unsigned short* __restrict__ A,
                                                     const unsigned short* __restrict__ B,
                                                     unsigned short* __restrict__ Part,
                                                     int M, int N, int K, int KH) {
  __shared__ unsigned short As[2][128 * 32];
  __shared__ unsigned short Bs[2][128 * 32];
  const int tid = threadIdx.x;
  const int bn = blockIdx.x * 128, bm = blockIdx.y * 128;
  const int kslice = blockIdx.z;
  const size_t koff = (size_t)kslice * KH;
  const int lane = tid & 63, wid = tid >> 6;
  const int lo = lane & 15, g = lane >> 4;
  const int wr = wid >> 2, wc = wid & 3;  // 2 x 4 wave grid, wave tile 64x32

  fx4 acc[4][2];
#pragma unroll
  for (int i = 0; i < 4; i++)
#pragma unroll
    for (int j = 0; j < 2; j++) acc[i][j] = zero4();

  const int srow = tid >> 2;                     // 0..127
  const int cg = (tid & 3) ^ ((srow >> 1) & 3);  // source chunk (pre-swizzled)
  const unsigned short* apg = &A[(size_t)(bm + srow) * K + koff + cg * 8];
  const unsigned short* bpg = &B[(size_t)(bn + srow) * K + koff + cg * 8];

  const int arow = wr * 64 + lo;  // +mi*16
  const int brow = wc * 32 + lo;  // +nj*16
  const int sc = (g ^ ((lo >> 1) & 3)) * 8;

#define G_STAGE(s, k0)                  \
  do {                                  \
    gl16(apg + (k0), &As[s][tid * 8]);  \
    gl16(bpg + (k0), &Bs[s][tid * 8]);  \
  } while (0)

#define G_COMPUTE(s)                                                   \
  do {                                                                 \
    bf16x8 af[4], bb[2];                                               \
    _Pragma("unroll") for (int mi = 0; mi < 4; mi++)                   \
        af[mi] = *(const bf16x8*)&As[s][(arow + mi * 16) * 32 + sc];   \
    _Pragma("unroll") for (int nj = 0; nj < 2; nj++)                   \
        bb[nj] = *(const bf16x8*)&Bs[s][(brow + nj * 16) * 32 + sc];   \
    _Pragma("unroll") for (int mi = 0; mi < 4; mi++)                   \
        _Pragma("unroll") for (int nj = 0; nj < 2; nj++)               \
            acc[mi][nj] = MFMA16(af[mi], bb[nj], acc[mi][nj]);         \
  } while (0)

  const int NT = KH >> 5;
  G_STAGE(0, 0);
  __syncthreads();
  int cur = 0;
  for (int t = 0; t < NT - 1; ++t) {
    G_STAGE(cur ^ 1, (t + 1) * 32);
    G_COMPUTE(cur);
    __syncthreads();
    cur ^= 1;
  }
  G_COMPUTE(cur);
#undef G_STAGE
#undef G_COMPUTE

  unsigned short* const pb = &Part[(size_t)kslice * M * N];
#pragma unroll
  for (int mi = 0; mi < 4; mi++)
#pragma unroll
    for (int nj = 0; nj < 2; nj++)
#pragma unroll
      for (int r = 0; r < 4; r++) {
        int row = bm + wr * 64 + mi * 16 + g * 4 + r;
        int col = bn + wc * 32 + nj * 16 + lo;
        pb[(size_t)row * N + col] = f2bf(acc[mi][nj][r]);
      }
}

// ---------------- combine 4 QKV partials + RoPE(Q,K) + V transpose ----------------
// blocks [0,2560): rope region (40 head-slices of 64: 32 Q + 8 K);
// blocks [2560,2816): V combine + transpose into Vt.
__global__ __launch_bounds__(256) void combine_qkv(const unsigned short* __restrict__ Pp,
                                                   unsigned short* __restrict__ qkv,
                                                   const float* __restrict__ cosp,
                                                   const float* __restrict__ sinp,
                                                   unsigned short* __restrict__ Vt) {
  __shared__ unsigned short t[64][72];
  const size_t pstr = (size_t)S_LEN * QKV_DIM;
  const int b = blockIdx.x;
  if (b < 2560) {
    int idx = b * 256 + threadIdx.x;
    int j = idx & 7;
    int tt = idx >> 3;
    int head = tt % 40;     // 0..31 Q, 32..39 K
    int s = tt / 40;
    const float scale = (head < 32) ? 0.125f * LOG2E : 1.0f;
    const size_t base = (size_t)s * QKV_DIM + head * 64 + j * 4;
    float xl[4] = {0.f, 0.f, 0.f, 0.f}, xh[4] = {0.f, 0.f, 0.f, 0.f};
#pragma unroll
    for (int z = 0; z < 4; z++) {
      ushort4 al = *(const ushort4*)&Pp[z * pstr + base];
      ushort4 ah = *(const ushort4*)&Pp[z * pstr + base + 32];
      xl[0] += bf2f(al.x); xl[1] += bf2f(al.y); xl[2] += bf2f(al.z); xl[3] += bf2f(al.w);
      xh[0] += bf2f(ah.x); xh[1] += bf2f(ah.y); xh[2] += bf2f(ah.z); xh[3] += bf2f(ah.w);
    }
    fx4 cl = *(const fx4*)&cosp[s * 64 + j * 4];
    fx4 ch = *(const fx4*)&cosp[s * 64 + 32 + j * 4];
    fx4 sl = *(const fx4*)&sinp[s * 64 + j * 4];
    fx4 sh = *(const fx4*)&sinp[s * 64 + 32 + j * 4];
    ushort4 ol, oh;
    ol.x = f2bf((xl[0] * cl[0] - xh[0] * sl[0]) * scale);
    ol.y = f2bf((xl[1] * cl[1] - xh[1] * sl[1]) * scale);
    ol.z = f2bf((xl[2] * cl[2] - xh[2] * sl[2]) * scale);
    ol.w = f2bf((xl[3] * cl[3] - xh[3] * sl[3]) * scale);
    oh.x = f2bf((xh[0] * ch[0] + xl[0] * sh[0]) * scale);
    oh.y = f2bf((xh[1] * ch[1] + xl[1] * sh[1]) * scale);
    oh.z = f2bf((xh[2] * ch[2] + xl[2] * sh[2]) * scale);
    oh.w = f2bf((xh[3] * ch[3] + xl[3] * sh[3]) * scale);
    *(ushort4*)&qkv[base] = ol;
    *(ushort4*)&qkv[base + 32] = oh;
  } else {
    const int tid = threadIdx.x;
    const int bb = b - 2560;       // 0..255
    const int cb = (bb & 7) * 64;  // V head-dim axis (0..511)
    const int rb = (bb >> 3) * 64; // seq axis
#pragma unroll
    for (int rr = 0; rr < 2; rr++) {
      int row = rr * 32 + (tid >> 3);
      int c8 = (tid & 7) * 8;
      const size_t src = (size_t)(rb + row) * QKV_DIM + V_OFF + cb + c8;
      float acc[8] = {0.f};
#pragma unroll
      for (int z = 0; z < 4; z++) {
        ush8 a = *(const ush8*)&Pp[z * pstr + src];
#pragma unroll
        for (int j = 0; j < 8; j++) acc[j] += bf2f(a[j]);
      }
      ush8 o;
#pragma unroll
      for (int j = 0; j < 8; j++) o[j] = f2bf(acc[j]);
      *(ush8*)&t[row][c8] = o;
    }
    __syncthreads();
#pragma unroll
    for (int rr = 0; rr < 2; rr++) {
      int col = rr * 32 + (tid >> 3);
      int r8 = (tid & 7) * 8;
      ush8 o;
#pragma unroll
      for (int j = 0; j < 8; j++) o[j] = t[r8 + j][col];
      *(ush8*)&Vt[(size_t)(cb + col) * S_LEN + rb + r8] = o;
    }
  }
}

// ---------------- combine 4 Wo partials -> fp32 output ----------------
__global__ __launch_bounds__(256) void combine_wo(const unsigned short* __restrict__ Pp,
                                                  float* __restrict__ out) {
  const size_t pstr = (size_t)S_LEN * QH_DIM;
  const int i = blockIdx.x * 256 + threadIdx.x;  // *8 elements
  const size_t base = (size_t)i * 8;
  float acc[8] = {0.f};
#pragma unroll
  for (int z = 0; z < 4; z++) {
    ush8 a = *(const ush8*)&Pp[z * pstr + base];
#pragma unroll
    for (int j = 0; j < 8; j++) acc[j] += bf2f(a[j]);
  }
  fx4 o0, o1;
#pragma unroll
  for (int j = 0; j < 4; j++) { o0[j] = acc[j]; o1[j] = acc[4 + j]; }
  *(fx4*)&out[base] = o0;
  *(fx4*)&out[base + 4] = o1;
}

// ---------------- single-pass fused causal attention, 8 waves ----------------
// Block = (head, 16 q-rows), 512 threads. Phase 1: 8 waves split k-range
// (kt = wid, wid+8, ...), QK^T+exp2 once -> bf16 e^s in [16][2048] swizzled
// LDS, partial l per wave. Barrier. Phase 2: wave w owns d-cols (w&3)*16 and
// k-parity (w>>2); partial oacc pairs reduced via LDS; P-store duty
// ((kt>>1)&3)==(w&3) interleaves the NT write stream with PV.
__global__ __launch_bounds__(512, 4) void attn_kernel(const unsigned short* __restrict__ Q,
                                                      const unsigned short* __restrict__ Kb,
                                                      const unsigned short* __restrict__ Vt,
                                                      float* __restrict__ P,
                                                      unsigned short* __restrict__ AO) {
  __shared__ unsigned short pls[16][2048];  // 64 KB: bf16 e^s, XOR-swizzled rows
  __shared__ float lred[8][16];
  __shared__ fx4 obuf[4][64];               // 4 KB: phase-2 pair reduction
  const int h = blockIdx.x;
  const int rt = 127 - blockIdx.y;  // heavy (long k-range) blocks dispatch first
  const int hkv = h >> 2;
  const int wid = threadIdx.x >> 6, lane = threadIdx.x & 63;
  const int lo = lane & 15, g = lane >> 4;
  const int rowb = rt * 16;
  const int nkt = (rt + 4) >> 2;  // ceil((rt+1)*16 / 64) k-tiles
  const int qg = rowb + lo;       // this lane's q row (phase 1)
  char* const plsb = (char*)pls;
  const int swz = (lo & 7) << 4;

  // beyond-range zero-fill of P (write-once NT stream)
  {
    const int zc0 = nkt * 64;
    const int nz4 = (S_LEN - zc0) >> 2;
    for (int idx = threadIdx.x; idx < 16 * nz4; idx += 512) {
      const int r = idx / nz4;
      const int c = idx - r * nz4;
      __builtin_nontemporal_store(zero4(),
          (fx4*)&P[((size_t)h * S_LEN + rowb + r) * S_LEN + zc0 + c * 4]);
    }
  }

  const bf16x8 qa0 = *(const bf16x8*)&Q[(size_t)qg * QKV_DIM + h * HD + g * 8];
  const bf16x8 qa1 = *(const bf16x8*)&Q[(size_t)qg * QKV_DIM + h * HD + 32 + g * 8];

  // ---- phase 1: QK^T + exp2 + pack, own k-tiles (kt = wid + 8j), partial l ----
  float l = 0.f;
  {
    bf16x8 kc0[4], kc1[4];
    if (wid < nkt) {
#pragma unroll
      for (int nj = 0; nj < 4; nj++) {
        const int kcol = wid * 64 + nj * 16 + lo;
        kc0[nj] = *(const bf16x8*)&Kb[(size_t)kcol * QKV_DIM + hkv * HD + g * 8];
        kc1[nj] = *(const bf16x8*)&Kb[(size_t)kcol * QKV_DIM + hkv * HD + 32 + g * 8];
      }
    }
    for (int kt = wid; kt < nkt; kt += 8) {
      bf16x8 kn0[4], kn1[4];
      if (kt + 8 < nkt) {  // register prefetch of next owned tile
#pragma unroll
        for (int nj = 0; nj < 4; nj++) {
          const int kcol = (kt + 8) * 64 + nj * 16 + lo;
          kn0[nj] = *(const bf16x8*)&Kb[(size_t)kcol * QKV_DIM + hkv * HD + g * 8];
          kn1[nj] = *(const bf16x8*)&Kb[(size_t)kcol * QKV_DIM + hkv * HD + 32 + g * 8];
        }
      }
      fx4 acc[4];
      __builtin_amdgcn_s_setprio(1);
#pragma unroll
      for (int nj = 0; nj < 4; nj++) {
        acc[nj] = MFMA16(kc0[nj], qa0, zero4());
        acc[nj] = MFMA16(kc1[nj], qa1, acc[nj]);
      }
      __builtin_amdgcn_s_setprio(0);
      const bool diag = (kt == nkt - 1);
#pragma unroll
      for (int nj = 0; nj < 4; nj++) {
        float e[4];
#pragma unroll
        for (int r = 0; r < 4; r++) {
          float v = exp2f(acc[nj][r]);
          if (diag && (kt * 64 + nj * 16 + g * 4 + r > qg)) v = 0.f;
          l += v;
          e[r] = v;
        }
        unsigned int w0 = (unsigned int)f2bf(e[0]) | ((unsigned int)f2bf(e[1]) << 16);
        unsigned int w1 = (unsigned int)f2bf(e[2]) | ((unsigned int)f2bf(e[3]) << 16);
        uint2 w; w.x = w0; w.y = w1;
        *(uint2*)(plsb + lo * 4096 + ((kt * 128 + nj * 32 + g * 8) ^ swz)) = w;
      }
#pragma unroll
      for (int j = 0; j < 4; j++) { kc0[j] = kn0[j]; kc1[j] = kn1[j]; }
    }
  }
  l += __shfl_xor(l, 16);
  l += __shfl_xor(l, 32);
  if (lane < 16) lred[wid][lo] = l;

  // phase-2 role: d-group + k-parity; V prefetch before barrier
  const int d0 = (wid & 3) * 16;
  const int par = wid >> 2;
  const unsigned short* const vrow = &Vt[(size_t)(hkv * HD + d0 + lo) * S_LEN];
  bf16x8 vc0 = *(const bf16x8*)&vrow[par * 64 + g * 8];
  bf16x8 vc1 = *(const bf16x8*)&vrow[par * 64 + 32 + g * 8];

  __syncthreads();

  // per-row 1/l for this lane's P-store rows (rho = it*4+g)
  float pinv[4];
#pragma unroll
  for (int it = 0; it < 4; it++) {
    const int rho = it * 4 + g;
    pinv[it] = 1.f / (lred[0][rho] + lred[1][rho] + lred[2][rho] + lred[3][rho] +
                      lred[4][rho] + lred[5][rho] + lred[6][rho] + lred[7][rho]);
  }
  float* const pbase = &P[((size_t)h * S_LEN + rowb) * S_LEN];

  // ---- phase 2: PV (own parity tiles) + interleaved P store ----
  fx4 oacc = zero4();
  for (int kt = par; kt < nkt; kt += 2) {
    bf16x8 vn0, vn1;
    if (kt + 2 < nkt) {
      vn0 = *(const bf16x8*)&vrow[(kt + 2) * 64 + g * 8];
      vn1 = *(const bf16x8*)&vrow[(kt + 2) * 64 + 32 + g * 8];
    }
    bf16x8 pa0 = *(const bf16x8*)(plsb + lo * 4096 + ((kt * 128 + g * 16) ^ swz));
    bf16x8 pa1 = *(const bf16x8*)(plsb + lo * 4096 + ((kt * 128 + 64 + g * 16) ^ swz));
    __builtin_amdgcn_s_setprio(1);
    oacc = MFMA16(pa0, vc0, oacc);
    oacc = MFMA16(pa1, vc1, oacc);
    __builtin_amdgcn_s_setprio(0);
    if (((kt >> 1) & 3) == (wid & 3)) {  // this wave stores P for this k-tile
#pragma unroll
      for (int it = 0; it < 4; it++) {
        const int rho = it * 4 + g;
        ushort4 b4 = *(const ushort4*)(plsb + rho * 4096 +
                                       ((kt * 128 + lo * 8) ^ ((rho & 7) << 4)));
        fx4 pv;
        pv[0] = bf2f(b4.x) * pinv[it]; pv[1] = bf2f(b4.y) * pinv[it];
        pv[2] = bf2f(b4.z) * pinv[it]; pv[3] = bf2f(b4.w) * pinv[it];
        __builtin_nontemporal_store(pv,
            (fx4*)&pbase[(size_t)rho * S_LEN + kt * 64 + lo * 4]);
      }
    }
    vc0 = vn0; vc1 = vn1;
  }

  // pair reduction: waves 4-7 publish partial oacc; waves 0-3 add + write AO
  if (par == 1) obuf[wid & 3][lane] = oacc;
  __syncthreads();
  if (par == 0) {
    fx4 o2 = obuf[wid][lane];
#pragma unroll
    for (int r = 0; r < 4; r++) {
      const int q = g * 4 + r;
      const float linv = 1.f / (lred[0][q] + lred[1][q] + lred[2][q] + lred[3][q] +
                                lred[4][q] + lred[5][q] + lred[6][q] + lred[7][q]);
      AO[(size_t)(rowb + q) * QH_DIM + h * HD + d0 + lo] = f2bf((oacc[r] + o2[r]) * linv);
    }
  }
}

extern "C" void kernel_launch(void* const* d_in, const int* in_sizes, int n_in,
                              void* d_out, int out_size, void* d_ws, size_t ws_size,
                              hipStream_t stream) {
  const float* hs = (const float*)d_in[0];
  const float* cosp = (const float*)d_in[1];
  const float* sinp = (const float*)d_in[2];
  // d_in[3] = attention_mask: pure causal, reconstructed in-kernel
  const float* Wq = (const float*)d_in[4];
  const float* Wk = (const float*)d_in[5];
  const float* Wv = (const float*)d_in[6];
  const float* Wo = (const float*)d_in[7];

  // workspace layout (Wo partials reuse hs/wqkv/qkv regions, all dead by step 5)
  char* w = (char*)d_ws;
  unsigned short* wo_bf   = (unsigned short*)(w);                        // 8.39 MB
  unsigned short* ao_bf   = (unsigned short*)(w + (((size_t)9) << 20));  // 8.39 MB
  unsigned short* hs_bf   = (unsigned short*)(w + (((size_t)18) << 20)); // 8.39 MB
  unsigned short* wqkv_bf = (unsigned short*)(w + (((size_t)27) << 20)); // 12.6 MB
  unsigned short* qkv_bf  = (unsigned short*)(w + (((size_t)40) << 20)); // 12.6 MB
  unsigned short* vt_bf   = (unsigned short*)(w + (((size_t)53) << 20)); // 2.1 MB
  unsigned short* wop     = hs_bf;  // Wo partials: 4 x 8.39 = 33.6 MB over 18..52 MB

  float* out0 = (float*)d_out;               // attn_output [S][2048]
  float* P = out0 + (size_t)S_LEN * QH_DIM;  // attn_weights [32][S][S]
  // QKV partials (4 x 12.6 = 50.3 MB bf16) live in the TAIL of P: written+read
  // before attn, then overwritten by attn's full P write. Zero extra workspace.
  const size_t P_BYTES = (size_t)NH * S_LEN * S_LEN * 4;
  const size_t QKVP_BYTES = (size_t)4 * S_LEN * QKV_DIM * 2;
  unsigned short* qkvp = (unsigned short*)((char*)P + P_BYTES - QKVP_BYTES);

  // 1. single fused cast (Wq/Wk/Wv stacked into one [3072][2048] bf16 B matrix)
  cast5<<<14336, 256, 0, stream>>>(hs, hs_bf, 1048576,
                                   Wq, wqkv_bf, 1048576,
                                   Wk, wqkv_bf + (size_t)K_OFF * 2048, 262144,
                                   Wv, wqkv_bf + (size_t)V_OFF * 2048, 262144,
                                   Wo, wo_bf, 1048576);

  // 2. split-K=4 QKV projection (1536 blocks) -> bf16 partials in P tail
  gemm_split<<<dim3(QKV_DIM / 128, 16, 4), 512, 0, stream>>>(hs_bf, wqkv_bf, qkvp,
                                                             2048, QKV_DIM, 2048, 512);

  // 3. combine 4 partials + RoPE(Q x0.125*log2e, K) + V transpose
  combine_qkv<<<2816, 256, 0, stream>>>(qkvp, qkv_bf, cosp, sinp, vt_bf);

  // 4. single-pass fused attention, 8 waves (attn_weights fp32 + context bf16)
  attn_kernel<<<dim3(NH, 128), 512, 0, stream>>>(qkv_bf, qkv_bf + K_OFF, vt_bf, P, ao_bf);

  // 5. split-K=4 output projection (1024 blocks) -> bf16 partials
  gemm_split<<<dim3(16, 16, 4), 512, 0, stream>>>(ao_bf, wo_bf, wop, 2048, 2048, 2048, 512);

  // 6. combine 4 Wo partials -> fp32 attn_output
  combine_wo<<<2048, 256, 0, stream>>>(wop, out0);
}

// Round 14
// 253.986 us; speedup vs baseline: 1.0313x; 1.0313x over previous
//
#include <hip/hip_runtime.h>

#define S_LEN 2048
#define NH 32
#define NKV 8
#define HD 64
#define QH_DIM (NH * HD)    // 2048
#define QKV_DIM 3072        // 2048 Q + 512 K + 512 V
#define K_OFF 2048
#define V_OFF 2560
#define LOG2E 1.44269504089f

typedef __attribute__((ext_vector_type(8))) __bf16 bf16x8;
typedef __attribute__((ext_vector_type(4))) float fx4;
typedef __attribute__((ext_vector_type(8))) unsigned short ush8;

__device__ __forceinline__ unsigned short f2bf(float f) {
  return __builtin_bit_cast(unsigned short, (__bf16)f);  // RNE; pairs fuse to v_cvt_pk_bf16_f32
}
__device__ __forceinline__ float bf2f(unsigned short h) {
  unsigned int u = ((unsigned int)h) << 16;
  return __builtin_bit_cast(float, u);
}
__device__ __forceinline__ fx4 zero4() {
  fx4 z; z[0] = 0.f; z[1] = 0.f; z[2] = 0.f; z[3] = 0.f; return z;
}

#define MFMA16(a, b, c) __builtin_amdgcn_mfma_f32_16x16x32_bf16((a), (b), (c), 0, 0, 0)

__device__ __forceinline__ void gl16(const void* g, void* l) {
  __builtin_amdgcn_global_load_lds((const __attribute__((address_space(1))) void*)g,
                                   (__attribute__((address_space(3))) void*)l, 16, 0, 0);
}

// ---------------- fused cast fp32 -> bf16 for 5 tensors ----------------
__global__ __launch_bounds__(256) void cast5(const float* __restrict__ s0, unsigned short* d0, int n0,
                                             const float* __restrict__ s1, unsigned short* d1, int n1,
                                             const float* __restrict__ s2, unsigned short* d2, int n2,
                                             const float* __restrict__ s3, unsigned short* d3, int n3,
                                             const float* __restrict__ s4, unsigned short* d4, int n4) {
  int i = blockIdx.x * 256 + threadIdx.x;
  const float* s;
  unsigned short* d;
  if (i < n0) { s = s0; d = d0; }
  else if ((i -= n0) < n1) { s = s1; d = d1; }
  else if ((i -= n1) < n2) { s = s2; d = d2; }
  else if ((i -= n2) < n3) { s = s3; d = d3; }
  else if ((i -= n3) < n4) { s = s4; d = d4; }
  else return;
  float4 v = ((const float4*)s)[i];
  ushort4 o;
  o.x = f2bf(v.x); o.y = f2bf(v.y); o.z = f2bf(v.z); o.w = f2bf(v.w);
  ((ushort4*)d)[i] = o;
}

// ---------------- split-K GEMM: Part[z][M][N] (bf16) = A[M][Kz] * B[N][Kz]^T ----
// 128x128 tile, BK=32, 8 waves, double-buffered 2-phase pipeline, 32 KB LDS.
__global__ __launch_bounds__(512, 6) void gemm_split(const unsigned short* __restrict__ A,
                                                     const unsigned short* __restrict__ B,
                                                     unsigned short* __restrict__ Part,
                                                     int M, int N, int K, int KH) {
  __shared__ unsigned short As[2][128 * 32];
  __shared__ unsigned short Bs[2][128 * 32];
  const int tid = threadIdx.x;
  const int bn = blockIdx.x * 128, bm = blockIdx.y * 128;
  const int kslice = blockIdx.z;
  const size_t koff = (size_t)kslice * KH;
  const int lane = tid & 63, wid = tid >> 6;
  const int lo = lane & 15, g = lane >> 4;
  const int wr = wid >> 2, wc = wid & 3;  // 2 x 4 wave grid, wave tile 64x32

  fx4 acc[4][2];
#pragma unroll
  for (int i = 0; i < 4; i++)
#pragma unroll
    for (int j = 0; j < 2; j++) acc[i][j] = zero4();

  const int srow = tid >> 2;                     // 0..127
  const int cg = (tid & 3) ^ ((srow >> 1) & 3);  // source chunk (pre-swizzled)
  const unsigned short* apg = &A[(size_t)(bm + srow) * K + koff + cg * 8];
  const unsigned short* bpg = &B[(size_t)(bn + srow) * K + koff + cg * 8];

  const int arow = wr * 64 + lo;  // +mi*16
  const int brow = wc * 32 + lo;  // +nj*16
  const int sc = (g ^ ((lo >> 1) & 3)) * 8;

#define G_STAGE(s, k0)                  \
  do {                                  \
    gl16(apg + (k0), &As[s][tid * 8]);  \
    gl16(bpg + (k0), &Bs[s][tid * 8]);  \
  } while (0)

#define G_COMPUTE(s)                                                   \
  do {                                                                 \
    bf16x8 af[4], bb[2];                                               \
    _Pragma("unroll") for (int mi = 0; mi < 4; mi++)                   \
        af[mi] = *(const bf16x8*)&As[s][(arow + mi * 16) * 32 + sc];   \
    _Pragma("unroll") for (int nj = 0; nj < 2; nj++)                   \
        bb[nj] = *(const bf16x8*)&Bs[s][(brow + nj * 16) * 32 + sc];   \
    _Pragma("unroll") for (int mi = 0; mi < 4; mi++)                   \
        _Pragma("unroll") for (int nj = 0; nj < 2; nj++)               \
            acc[mi][nj] = MFMA16(af[mi], bb[nj], acc[mi][nj]);         \
  } while (0)

  const int NT = KH >> 5;
  G_STAGE(0, 0);
  __syncthreads();
  int cur = 0;
  for (int t = 0; t < NT - 1; ++t) {
    G_STAGE(cur ^ 1, (t + 1) * 32);
    G_COMPUTE(cur);
    __syncthreads();
    cur ^= 1;
  }
  G_COMPUTE(cur);
#undef G_STAGE
#undef G_COMPUTE

  unsigned short* const pb = &Part[(size_t)kslice * M * N];
#pragma unroll
  for (int mi = 0; mi < 4; mi++)
#pragma unroll
    for (int nj = 0; nj < 2; nj++)
#pragma unroll
      for (int r = 0; r < 4; r++) {
        int row = bm + wr * 64 + mi * 16 + g * 4 + r;
        int col = bn + wc * 32 + nj * 16 + lo;
        pb[(size_t)row * N + col] = f2bf(acc[mi][nj][r]);
      }
}

// ---------------- combine QKV partials + RoPE(Q,K) + V transpose ----------------
__global__ __launch_bounds__(256) void combine_qkv(const unsigned short* __restrict__ P0,
                                                   const unsigned short* __restrict__ P1,
                                                   unsigned short* __restrict__ qkv,
                                                   const float* __restrict__ cosp,
                                                   const float* __restrict__ sinp,
                                                   unsigned short* __restrict__ Vt) {
  __shared__ unsigned short t[64][72];
  const int b = blockIdx.x;
  if (b < 2560) {
    int idx = b * 256 + threadIdx.x;
    int j = idx & 7;
    int tt = idx >> 3;
    int head = tt % 40;     // 0..31 Q, 32..39 K
    int s = tt / 40;
    const float scale = (head < 32) ? 0.125f * LOG2E : 1.0f;
    const size_t base = (size_t)s * QKV_DIM + head * 64 + j * 4;
    ushort4 a0l = *(const ushort4*)&P0[base];
    ushort4 a1l = *(const ushort4*)&P1[base];
    ushort4 a0h = *(const ushort4*)&P0[base + 32];
    ushort4 a1h = *(const ushort4*)&P1[base + 32];
    float xl0 = bf2f(a0l.x) + bf2f(a1l.x), xl1 = bf2f(a0l.y) + bf2f(a1l.y);
    float xl2 = bf2f(a0l.z) + bf2f(a1l.z), xl3 = bf2f(a0l.w) + bf2f(a1l.w);
    float xh0 = bf2f(a0h.x) + bf2f(a1h.x), xh1 = bf2f(a0h.y) + bf2f(a1h.y);
    float xh2 = bf2f(a0h.z) + bf2f(a1h.z), xh3 = bf2f(a0h.w) + bf2f(a1h.w);
    fx4 cl = *(const fx4*)&cosp[s * 64 + j * 4];
    fx4 ch = *(const fx4*)&cosp[s * 64 + 32 + j * 4];
    fx4 sl = *(const fx4*)&sinp[s * 64 + j * 4];
    fx4 sh = *(const fx4*)&sinp[s * 64 + 32 + j * 4];
    ushort4 ol, oh;
    ol.x = f2bf((xl0 * cl[0] - xh0 * sl[0]) * scale);
    ol.y = f2bf((xl1 * cl[1] - xh1 * sl[1]) * scale);
    ol.z = f2bf((xl2 * cl[2] - xh2 * sl[2]) * scale);
    ol.w = f2bf((xl3 * cl[3] - xh3 * sl[3]) * scale);
    oh.x = f2bf((xh0 * ch[0] + xl0 * sh[0]) * scale);
    oh.y = f2bf((xh1 * ch[1] + xl1 * sh[1]) * scale);
    oh.z = f2bf((xh2 * ch[2] + xl2 * sh[2]) * scale);
    oh.w = f2bf((xh3 * ch[3] + xl3 * sh[3]) * scale);
    *(ushort4*)&qkv[base] = ol;
    *(ushort4*)&qkv[base + 32] = oh;
  } else {
    const int tid = threadIdx.x;
    const int bb = b - 2560;       // 0..255
    const int cb = (bb & 7) * 64;  // V head-dim axis (0..511)
    const int rb = (bb >> 3) * 64; // seq axis
#pragma unroll
    for (int rr = 0; rr < 2; rr++) {
      int row = rr * 32 + (tid >> 3);
      int c8 = (tid & 7) * 8;
      const size_t src = (size_t)(rb + row) * QKV_DIM + V_OFF + cb + c8;
      ush8 a = *(const ush8*)&P0[src];
      ush8 c = *(const ush8*)&P1[src];
      ush8 o;
#pragma unroll
      for (int j = 0; j < 8; j++) o[j] = f2bf(bf2f(a[j]) + bf2f(c[j]));
      *(ush8*)&t[row][c8] = o;
    }
    __syncthreads();
#pragma unroll
    for (int rr = 0; rr < 2; rr++) {
      int col = rr * 32 + (tid >> 3);
      int r8 = (tid & 7) * 8;
      ush8 o;
#pragma unroll
      for (int j = 0; j < 8; j++) o[j] = t[r8 + j][col];
      *(ush8*)&Vt[(size_t)(cb + col) * S_LEN + rb + r8] = o;
    }
  }
}

// ---------------- combine Wo partials -> fp32 output ----------------
__global__ __launch_bounds__(256) void combine_wo(const unsigned short* __restrict__ P0,
                                                  const unsigned short* __restrict__ P1,
                                                  float* __restrict__ out) {
  const int i = blockIdx.x * 256 + threadIdx.x;  // *8 elements
  const size_t base = (size_t)i * 8;
  ush8 a = *(const ush8*)&P0[base];
  ush8 b = *(const ush8*)&P1[base];
  fx4 o0, o1;
#pragma unroll
  for (int j = 0; j < 4; j++) o0[j] = bf2f(a[j]) + bf2f(b[j]);
#pragma unroll
  for (int j = 0; j < 4; j++) o1[j] = bf2f(a[4 + j]) + bf2f(b[4 + j]);
  *(fx4*)&out[base] = o0;
  *(fx4*)&out[base + 4] = o1;
}

// ---------------- single-pass FUSED-SWEEP causal attention, 8 waves ----------------
// Block = (head, 16 q-rows), 512 threads. ONE k-sweep: wave owns tiles
// kt%8==wid; per tile: QK^T (swapped) -> exp2 -> pack bf16 e^s to pls
// (wave-local write) -> read back -> PV MFMA over ALL 4 d-groups into
// per-wave partial oacc. Then: l-reduce barrier; P-store sweep (pure NT
// stream, own tiles); barrier; 8-way oacc reduction through pls space.
__global__ __launch_bounds__(512, 4) void attn_kernel(const unsigned short* __restrict__ Q,
                                                      const unsigned short* __restrict__ Kb,
                                                      const unsigned short* __restrict__ Vt,
                                                      float* __restrict__ P,
                                                      unsigned short* __restrict__ AO) {
  __shared__ __align__(16) unsigned short pls[16][2048];  // 64 KB e^s / reduce scratch
  __shared__ float lred[8][16];
  const int h = blockIdx.x;
  const int rt = 127 - blockIdx.y;  // heavy (long k-range) blocks dispatch first
  const int hkv = h >> 2;
  const int wid = threadIdx.x >> 6, lane = threadIdx.x & 63;
  const int lo = lane & 15, g = lane >> 4;
  const int rowb = rt * 16;
  const int nkt = (rt + 4) >> 2;  // ceil((rt+1)*16 / 64) k-tiles
  const int qg = rowb + lo;       // this lane's q row
  char* const plsb = (char*)pls;
  const int swz = (lo & 7) << 4;

  // beyond-range zero-fill of P (write-once NT stream)
  {
    const int zc0 = nkt * 64;
    const int nz4 = (S_LEN - zc0) >> 2;
    for (int idx = threadIdx.x; idx < 16 * nz4; idx += 512) {
      const int r = idx / nz4;
      const int c = idx - r * nz4;
      __builtin_nontemporal_store(zero4(),
          (fx4*)&P[((size_t)h * S_LEN + rowb + r) * S_LEN + zc0 + c * 4]);
    }
  }

  const bf16x8 qa0 = *(const bf16x8*)&Q[(size_t)qg * QKV_DIM + h * HD + g * 8];
  const bf16x8 qa1 = *(const bf16x8*)&Q[(size_t)qg * QKV_DIM + h * HD + 32 + g * 8];

  float l = 0.f;
  fx4 oacc[4];
#pragma unroll
  for (int dj = 0; dj < 4; dj++) oacc[dj] = zero4();

  // ---- fused sweep: QK^T + exp2 + pack + PV, own k-tiles (kt = wid + 8j) ----
  {
    bf16x8 kc0[4], kc1[4];
    if (wid < nkt) {
#pragma unroll
      for (int nj = 0; nj < 4; nj++) {
        const int kcol = wid * 64 + nj * 16 + lo;
        kc0[nj] = *(const bf16x8*)&Kb[(size_t)kcol * QKV_DIM + hkv * HD + g * 8];
        kc1[nj] = *(const bf16x8*)&Kb[(size_t)kcol * QKV_DIM + hkv * HD + 32 + g * 8];
      }
    }
    for (int kt = wid; kt < nkt; kt += 8) {
      bf16x8 kn0[4], kn1[4];
      if (kt + 8 < nkt) {  // register prefetch of next owned tile
#pragma unroll
        for (int nj = 0; nj < 4; nj++) {
          const int kcol = (kt + 8) * 64 + nj * 16 + lo;
          kn0[nj] = *(const bf16x8*)&Kb[(size_t)kcol * QKV_DIM + hkv * HD + g * 8];
          kn1[nj] = *(const bf16x8*)&Kb[(size_t)kcol * QKV_DIM + hkv * HD + 32 + g * 8];
        }
      }
      fx4 acc[4];
      __builtin_amdgcn_s_setprio(1);
#pragma unroll
      for (int nj = 0; nj < 4; nj++) {
        acc[nj] = MFMA16(kc0[nj], qa0, zero4());
        acc[nj] = MFMA16(kc1[nj], qa1, acc[nj]);
      }
      __builtin_amdgcn_s_setprio(0);
      const bool diag = (kt == nkt - 1);
#pragma unroll
      for (int nj = 0; nj < 4; nj++) {
        float e[4];
#pragma unroll
        for (int r = 0; r < 4; r++) {
          float v = exp2f(acc[nj][r]);
          if (diag && (kt * 64 + nj * 16 + g * 4 + r > qg)) v = 0.f;
          l += v;
          e[r] = v;
        }
        unsigned int w0 = (unsigned int)f2bf(e[0]) | ((unsigned int)f2bf(e[1]) << 16);
        unsigned int w1 = (unsigned int)f2bf(e[2]) | ((unsigned int)f2bf(e[3]) << 16);
        uint2 w; w.x = w0; w.y = w1;
        *(uint2*)(plsb + lo * 4096 + ((kt * 128 + nj * 32 + g * 8) ^ swz)) = w;
      }
      // PV for this tile over ALL 4 d-groups (pls read is wave-local: same
      // wave wrote this tile region just above -> in-wave DS ordering)
#pragma unroll
      for (int kk = 0; kk < 2; kk++) {
        bf16x8 pa = *(const bf16x8*)(plsb + lo * 4096 + ((kt * 128 + kk * 64 + g * 16) ^ swz));
        __builtin_amdgcn_s_setprio(1);
#pragma unroll
        for (int dj = 0; dj < 4; dj++) {
          bf16x8 vb = *(const bf16x8*)&Vt[(size_t)(hkv * HD + dj * 16 + lo) * S_LEN +
                                          kt * 64 + kk * 32 + g * 8];
          oacc[dj] = MFMA16(pa, vb, oacc[dj]);
        }
        __builtin_amdgcn_s_setprio(0);
      }
#pragma unroll
      for (int j = 0; j < 4; j++) { kc0[j] = kn0[j]; kc1[j] = kn1[j]; }
    }
  }
  l += __shfl_xor(l, 16);
  l += __shfl_xor(l, 32);
  if (lane < 16) lred[wid][lo] = l;

  __syncthreads();  // pls + lred complete

  // per-row 1/l for this lane's P-store rows (rho = it*4+g)
  float pinv[4];
#pragma unroll
  for (int it = 0; it < 4; it++) {
    const int rho = it * 4 + g;
    pinv[it] = 1.f / (lred[0][rho] + lred[1][rho] + lred[2][rho] + lred[3][rho] +
                      lred[4][rho] + lred[5][rho] + lred[6][rho] + lred[7][rho]);
  }
  float* const pbase = &P[((size_t)h * S_LEN + rowb) * S_LEN];

  // ---- P-store sweep: pure NT stream over own tiles ----
  for (int kt = wid; kt < nkt; kt += 8) {
#pragma unroll
    for (int it = 0; it < 4; it++) {
      const int rho = it * 4 + g;
      ushort4 b4 = *(const ushort4*)(plsb + rho * 4096 +
                                     ((kt * 128 + lo * 8) ^ ((rho & 7) << 4)));
      fx4 pv;
      pv[0] = bf2f(b4.x) * pinv[it]; pv[1] = bf2f(b4.y) * pinv[it];
      pv[2] = bf2f(b4.z) * pinv[it]; pv[3] = bf2f(b4.w) * pinv[it];
      __builtin_nontemporal_store(pv,
          (fx4*)&pbase[(size_t)rho * S_LEN + kt * 64 + lo * 4]);
    }
  }

  // ---- 8-way oacc reduction through pls space (dead now) ----
  __syncthreads();  // all P-store reads of pls done
  fx4* const obp = (fx4*)plsb;  // [8 waves][4 d-groups][64 lanes]
#pragma unroll
  for (int dj = 0; dj < 4; dj++) obp[wid * 256 + dj * 64 + lane] = oacc[dj];
  __syncthreads();
  if (wid < 4) {
    fx4 s = obp[wid * 64 + lane];
#pragma unroll
    for (int ww = 1; ww < 8; ww++) {
      fx4 t2 = obp[ww * 256 + wid * 64 + lane];
#pragma unroll
      for (int j = 0; j < 4; j++) s[j] += t2[j];
    }
#pragma unroll
    for (int r = 0; r < 4; r++) {
      const int q = g * 4 + r;
      const float linv = 1.f / (lred[0][q] + lred[1][q] + lred[2][q] + lred[3][q] +
                                lred[4][q] + lred[5][q] + lred[6][q] + lred[7][q]);
      AO[(size_t)(rowb + q) * QH_DIM + h * HD + wid * 16 + lo] = f2bf(s[r] * linv);
    }
  }
}

extern "C" void kernel_launch(void* const* d_in, const int* in_sizes, int n_in,
                              void* d_out, int out_size, void* d_ws, size_t ws_size,
                              hipStream_t stream) {
  const float* hs = (const float*)d_in[0];
  const float* cosp = (const float*)d_in[1];
  const float* sinp = (const float*)d_in[2];
  // d_in[3] = attention_mask: pure causal, reconstructed in-kernel
  const float* Wq = (const float*)d_in[4];
  const float* Wk = (const float*)d_in[5];
  const float* Wv = (const float*)d_in[6];
  const float* Wo = (const float*)d_in[7];

  // workspace layout (Wo partials reuse hs/wqkv region, dead by then)
  char* w = (char*)d_ws;
  unsigned short* wo_bf   = (unsigned short*)(w);                        // 8.39 MB
  unsigned short* ao_bf   = (unsigned short*)(w + (((size_t)9) << 20));  // 8.39 MB
  unsigned short* hs_bf   = (unsigned short*)(w + (((size_t)18) << 20)); // 8.39 MB
  unsigned short* wqkv_bf = (unsigned short*)(w + (((size_t)27) << 20)); // 12.6 MB
  unsigned short* qkv_bf  = (unsigned short*)(w + (((size_t)40) << 20)); // 12.6 MB
  unsigned short* vt_bf   = (unsigned short*)(w + (((size_t)53) << 20)); // 2.1 MB
  unsigned short* wop     = hs_bf;  // Wo partials: 16.8 MB over hs+wqkv (dead)

  float* out0 = (float*)d_out;               // attn_output [S][2048]
  float* P = out0 + (size_t)S_LEN * QH_DIM;  // attn_weights [32][S][S]
  // QKV partials (25.2 MB bf16) live in the TAIL of P: written+read before
  // attn, then overwritten by attn's full P write. Zero extra workspace.
  const size_t P_BYTES = (size_t)NH * S_LEN * S_LEN * 4;
  const size_t QKVP_BYTES = (size_t)2 * S_LEN * QKV_DIM * 2;
  unsigned short* qkvp = (unsigned short*)((char*)P + P_BYTES - QKVP_BYTES);

  // 1. single fused cast (Wq/Wk/Wv stacked into one [3072][2048] bf16 B matrix)
  cast5<<<14336, 256, 0, stream>>>(hs, hs_bf, 1048576,
                                   Wq, wqkv_bf, 1048576,
                                   Wk, wqkv_bf + (size_t)K_OFF * 2048, 262144,
                                   Wv, wqkv_bf + (size_t)V_OFF * 2048, 262144,
                                   Wo, wo_bf, 1048576);

  // 2. split-K=2 QKV projection (768 blocks, 3/CU) -> bf16 partials in P tail
  gemm_split<<<dim3(QKV_DIM / 128, 16, 2), 512, 0, stream>>>(hs_bf, wqkv_bf, qkvp,
                                                             2048, QKV_DIM, 2048, 1024);

  // 3. combine partials + RoPE(Q x0.125*log2e, K) + V transpose
  combine_qkv<<<2816, 256, 0, stream>>>(qkvp, qkvp + (size_t)S_LEN * QKV_DIM,
                                        qkv_bf, cosp, sinp, vt_bf);

  // 4. fused-sweep attention, 8 waves (attn_weights fp32 + context bf16)
  attn_kernel<<<dim3(NH, 128), 512, 0, stream>>>(qkv_bf, qkv_bf + K_OFF, vt_bf, P, ao_bf);

  // 5. split-K=2 output projection (512 blocks, 2/CU) -> bf16 partials
  gemm_split<<<dim3(16, 16, 2), 512, 0, stream>>>(ao_bf, wo_bf, wop, 2048, 2048, 2048, 1024);

  // 6. combine Wo partials -> fp32 attn_output
  combine_wo<<<2048, 256, 0, stream>>>(wop, wop + (size_t)S_LEN * QH_DIM, out0);
}